// Round 9
// baseline (230.584 us; speedup 1.0000x reference)
//
#include <hip/hip_runtime.h>
#include <hip/hip_bf16.h>
#include <stdint.h>

// GCN layer: out = D^-1/2 (A+I) D^-1/2 (x W + b)
// N=100000 nodes, E=3.2M edges, 256 -> 128 features.
// Pipeline: W pre-cast to bf16 [col][k] -> bucket histogram/scan -> LDS-staged
// partition (512 rows/bucket, burst writes) -> per-bucket CSR build (1024 thr,
// produces deg -> dis, adjacency SORTED BY SOURCE BAND c>>12 so concurrent
// aggregate waves share an L2-resident ~1MB band of hu) -> bf16 MFMA GEMM
// (stores hu' = bf16(dis*h)) -> wave-per-node gather, scalar addressing.

#define RB    512      // rows per bucket
#define RBSH  9
#define NBMAX 256      // >= NB = ceil(100000/512) = 196
#define CHUNK 12288    // edges per partition block (LDS sorted array = 48 KB)
#define NSL   32       // source bands for adjacency sort (c >> 12)
#define SLSH  12

typedef __attribute__((ext_vector_type(8))) short short8v;   // 8 bf16
typedef __attribute__((ext_vector_type(16))) float f32x16;

__device__ __forceinline__ float bf_lo(uint32_t p) { return __uint_as_float(p << 16); }
__device__ __forceinline__ float bf_hi(uint32_t p) { return __uint_as_float(p & 0xffff0000u); }

__device__ __forceinline__ uint32_t f2bf(float f) {
  uint32_t u = __float_as_uint(f);
  return (u + 0x7fffu + ((u >> 16) & 1u)) >> 16;  // RNE
}

// HW pack-convert: (lo, hi) -> (bf16(hi)<<16)|bf16(lo), RNE via v_cvt_pk_bf16_f32
__device__ __forceinline__ uint32_t cvt_pk(float lo, float hi) {
  __hip_bfloat162 b = __float22bfloat162_rn(float2{lo, hi});
  union { __hip_bfloat162 b; uint32_t u; } cv;
  cv.b = b;
  return cv.u;
}

// ---- W cast: wbf[col*256 + k] = bf16(W[k*128 + col]) ----
__global__ void k_wcast(const float* __restrict__ W, uint16_t* __restrict__ wbf) {
  int t = blockIdx.x * 256 + threadIdx.x;   // 32768 total
  int col = t >> 8, k = t & 255;
  wbf[t] = (uint16_t)f2bf(W[k * 128 + col]);
}

// ---- bucket histogram (LDS-staged, few global atomics) ----
__launch_bounds__(256)
__global__ void k_bhist(const int* __restrict__ rows, int E, int NB,
                        int* __restrict__ bcnt) {
  __shared__ int h[NBMAX];
  int tid = threadIdx.x;
  for (int i = tid; i < NBMAX; i += 256) h[i] = 0;
  __syncthreads();
  int stride = gridDim.x * 256;
  for (int e = blockIdx.x * 256 + tid; e < E; e += stride)
    atomicAdd(&h[rows[e] >> RBSH], 1);
  __syncthreads();
  for (int b = tid; b < NB; b += 256)
    if (h[b]) atomicAdd(&bcnt[b], h[b]);
}

// ---- exclusive scan of bucket counts (single block, n <= 2048) ----
__global__ void k_scanb(const int* __restrict__ bcnt, int n,
                        int* __restrict__ gbase, int* __restrict__ gcur) {
  __shared__ int s[2048];
  int t = threadIdx.x;  // 1024 threads
  int v0 = (t < n) ? bcnt[t] : 0;
  int v1 = (t + 1024 < n) ? bcnt[t + 1024] : 0;
  s[t] = v0; s[t + 1024] = v1;
  __syncthreads();
  for (int d = 1; d < 2048; d <<= 1) {
    int a0 = (t >= d) ? s[t - d] : 0;
    int a1 = s[t + 1024 - d];
    __syncthreads();
    s[t] += a0; s[t + 1024] += a1;
    __syncthreads();
  }
  if (t < n)        { int e = s[t] - v0;        gbase[t] = e;        gcur[t] = e; }
  if (t + 1024 < n) { int e = s[t + 1024] - v1; gbase[t + 1024] = e; gcur[t + 1024] = e; }
}

// ---- LDS-staged partition: chunk -> bucket-sorted runs -> burst copy-out ----
__launch_bounds__(1024)
__global__ void k_part(const int* __restrict__ rows, const int* __restrict__ cols,
                       int E, int NB, int* __restrict__ gcur,
                       uint32_t* __restrict__ temp) {
  __shared__ uint32_t sorted[CHUNK];  // 48 KB
  __shared__ int hist[NBMAX];
  __shared__ int scanv[NBMAX];
  __shared__ int res[NBMAX];
  int tid = threadIdx.x;
  int base = blockIdx.x * CHUNK;
  int cnt = min(CHUNK, E - base);

  for (int i = tid; i < NBMAX; i += 1024) hist[i] = 0;
  __syncthreads();
  for (int i = tid; i < cnt; i += 1024)
    atomicAdd(&hist[rows[base + i] >> RBSH], 1);
  __syncthreads();
  if (tid < NBMAX) scanv[tid] = hist[tid];
  __syncthreads();
  for (int d = 1; d < NBMAX; d <<= 1) {
    int v = 0;
    if (tid < NBMAX && tid >= d) v = scanv[tid - d];
    __syncthreads();
    if (tid < NBMAX) scanv[tid] += v;
    __syncthreads();
  }
  if (tid < NB) {
    int c = hist[tid];
    res[tid] = c ? atomicAdd(&gcur[tid], c) : 0;  // one reservation per bucket
    hist[tid] = scanv[tid] - c;                   // lbase -> cursor
  }
  __syncthreads();
  for (int i = tid; i < cnt; i += 1024) {
    int r = rows[base + i];
    int c = cols[base + i];
    int b = r >> RBSH;
    int p = atomicAdd(&hist[b], 1);
    sorted[p] = ((uint32_t)(r & (RB - 1)) << 17) | (uint32_t)c;
  }
  __syncthreads();
  int wv = tid >> 6, lane = tid & 63;
  for (int b = wv; b < NB; b += 16) {   // wave-cooperative contiguous run copy
    int st = b ? scanv[b - 1] : 0;
    int en = scanv[b];
    int gb = res[b];
    for (int j = st + lane; j < en; j += 64)
      temp[gb + (j - st)] = sorted[j];
  }
}

// ---- per-bucket CSR build (1024 thr); emits deg -> dis; adjacency sorted
// by source band (c >> SLSH) within each node via per-(node,band) cursors ----
__launch_bounds__(1024)
__global__ void k_csr_build(const int* __restrict__ gbase, const int* __restrict__ bcnt,
                            const uint32_t* __restrict__ temp, int N,
                            int* __restrict__ offs, float* __restrict__ dis,
                            int* __restrict__ csr) {
  __shared__ int cnt2[NSL * RB];  // [band][node], 64 KB: count -> cursor
  __shared__ int S[256];
  __shared__ int nbase[RB];       // within-bucket exclusive base per node
  int b = blockIdx.x;
  int tid = threadIdx.x;
  int base = gbase[b];
  int cb = bcnt[b];

  for (int i = tid; i < NSL * RB; i += 1024) cnt2[i] = 0;
  __syncthreads();
  for (int i = tid; i < cb; i += 1024) {
    uint32_t pk = temp[base + i];
    atomicAdd(&cnt2[((pk & 0x1FFFF) >> SLSH) * RB + (pk >> 17)], 1);
  }
  __syncthreads();
  int a0 = 0, a1 = 0, ex0 = 0;
  if (tid < 256) {
    int n0 = 2 * tid, n1 = 2 * tid + 1;
#pragma unroll
    for (int s = 0; s < NSL; ++s) {
      a0 += cnt2[s * RB + n0];
      a1 += cnt2[s * RB + n1];
    }
    S[tid] = a0 + a1;
  }
  __syncthreads();
  for (int d = 1; d < 256; d <<= 1) {
    int v = 0;
    if (tid < 256 && tid >= d) v = S[tid - d];
    __syncthreads();
    if (tid < 256) S[tid] += v;
    __syncthreads();
  }
  if (tid < 256) {
    ex0 = S[tid] - (a0 + a1);
    int r0 = b * RB + 2 * tid;
    if (r0 < N)     { dis[r0]     = rsqrtf((float)(a0 + 1)); offs[r0]     = base + ex0; }
    if (r0 + 1 < N) { dis[r0 + 1] = rsqrtf((float)(a1 + 1)); offs[r0 + 1] = base + ex0 + a0; }
    nbase[2 * tid]     = ex0;
    nbase[2 * tid + 1] = ex0 + a0;
  }
  __syncthreads();
  if (tid < RB) {                 // per-node band scan -> cursors
    int run = nbase[tid];
#pragma unroll
    for (int s = 0; s < NSL; ++s) {
      int t = cnt2[s * RB + tid];
      cnt2[s * RB + tid] = run;
      run += t;
    }
  }
  __syncthreads();
  for (int i = tid; i < cb; i += 1024) {
    uint32_t pk = temp[base + i];
    int lrow = pk >> 17;
    int c = (int)(pk & 0x1FFFF);
    int p = atomicAdd(&cnt2[(c >> SLSH) * RB + lrow], 1);
    csr[base + p] = c;
  }
}

// ---- bf16 MFMA GEMM: h = x W + b; store hu[m*64+j] = bf16(dis[m]*h) pair ----
// Block: 256 thr = 4 waves, M-tile 64, all 128 cols. Wave w: rows
// [32(w&1),+32), cols [64(w>>1),+64) as two 32x32 tiles. A-frags straight
// from global (x rows used once, v_cvt_pk to bf16); W in LDS bf16 [col][k],
// 16B-slot XOR swizzle (slot^=col&31) => conflict-free b128 read & write.
// hu dword j packs feats (p, p+32), p = (j&31) | ((j&32)<<1).
__launch_bounds__(256)
__global__ void k_gemm(const float* __restrict__ x, const uint16_t* __restrict__ wbf,
                       const float* __restrict__ bias, const float* __restrict__ dis,
                       uint32_t* __restrict__ hu, int M) {
  __shared__ uint16_t wlds[32768];  // 64 KB -> 2 blocks/CU
  int tid = threadIdx.x;
  {
    const uint4* src = (const uint4*)wbf;
#pragma unroll
    for (int i = 0; i < 16; ++i) {
      int chunk = i * 256 + tid;       // 16B chunks: col = chunk>>5, slot = chunk&31
      uint4 v = src[chunk];
      int col = chunk >> 5, s = chunk & 31;
      int sp = s ^ (col & 31);
      *(uint4*)&wlds[col * 256 + sp * 8] = v;
    }
  }
  int w = tid >> 6, l = tid & 63;
  int lr = l & 31, g = l >> 5;
  int row = blockIdx.x * 64 + (w & 1) * 32 + lr;
  int c0 = (w >> 1) * 64;
  bool valid = row < M;
  const float* xrow = x + (size_t)row * 256;
  f32x16 acc0 = {}, acc1 = {};
  __syncthreads();
#pragma unroll
  for (int kt = 0; kt < 16; ++kt) {
    int k0 = kt * 16 + g * 8;          // lane's 8 contiguous k
    float4 f0 = make_float4(0.f, 0.f, 0.f, 0.f), f1 = f0;
    if (valid) {
      f0 = *(const float4*)(xrow + k0);
      f1 = *(const float4*)(xrow + k0 + 4);
    }
    union { uint32_t u[4]; short8v v; } av;
    av.u[0] = cvt_pk(f0.x, f0.y);
    av.u[1] = cvt_pk(f0.z, f0.w);
    av.u[2] = cvt_pk(f1.x, f1.y);
    av.u[3] = cvt_pk(f1.z, f1.w);
    int sp = (kt * 2 + g) ^ lr;        // swizzled 16B slot
    short8v b0 = *(short8v*)&wlds[(c0 + lr) * 256 + sp * 8];
    short8v b1 = *(short8v*)&wlds[(c0 + 32 + lr) * 256 + sp * 8];
    acc0 = __builtin_amdgcn_mfma_f32_32x32x16_bf16(av.v, b0, acc0, 0, 0, 0);
    acc1 = __builtin_amdgcn_mfma_f32_32x32x16_bf16(av.v, b1, acc1, 0, 0, 0);
  }
  int j = lr + (w >> 1) * 32;          // hu pair index
  int p = c0 + lr;                     // actual feature col of tile0
  float bl = bias[p], bh = bias[p + 32];
#pragma unroll
  for (int r = 0; r < 16; ++r) {
    int mrow = blockIdx.x * 64 + (w & 1) * 32 + (r & 3) + 8 * (r >> 2) + 4 * g;
    if (mrow < M) {
      float di = dis[mrow];
      hu[(size_t)mrow * 64 + j] = cvt_pk(di * (acc0[r] + bl), di * (acc1[r] + bh));
    }
  }
}

// ---- aggregation: wave per node, scalar addressing, 8 gathers in flight ----
// e/end readfirstlane'd -> csr reads on the scalar pipe, hu row base SGPR +
// loop-invariant lane offset. csr is band-sorted, so concurrent waves gather
// from the same ~1MB band of hu (L2-resident).
__launch_bounds__(256)
__global__ void k_aggregate(const uint32_t* __restrict__ hu, const float* __restrict__ dis,
                            const int* __restrict__ offs, const int* __restrict__ csr,
                            float* __restrict__ out, int N, int E) {
  int wid = blockIdx.x * 4 + (threadIdx.x >> 6);
  int lane = threadIdx.x & 63;
  if (wid >= N) return;
  int e0  = __builtin_amdgcn_readfirstlane(offs[wid]);
  int end = __builtin_amdgcn_readfirstlane((wid + 1 < N) ? offs[wid + 1] : E);
  int cnt = end - e0;
  const int* cp = csr + e0;                       // uniform (SGPR) base
  const uint32_t* hrow = hu + ((size_t)(uint32_t)wid << 6);
  uint32_t ps = hrow[lane];
  float ax = bf_lo(ps);   // self loop: hu' already has dis folded in
  float ay = bf_hi(ps);
  int i = 0;
  for (; i + 8 <= cnt; i += 8) {                  // 8 independent gathers in flight
    int c0 = cp[i],     c1 = cp[i + 1], c2 = cp[i + 2], c3 = cp[i + 3];
    int c4 = cp[i + 4], c5 = cp[i + 5], c6 = cp[i + 6], c7 = cp[i + 7];
    uint32_t p0 = hu[((size_t)(uint32_t)c0 << 6) + lane];
    uint32_t p1 = hu[((size_t)(uint32_t)c1 << 6) + lane];
    uint32_t p2 = hu[((size_t)(uint32_t)c2 << 6) + lane];
    uint32_t p3 = hu[((size_t)(uint32_t)c3 << 6) + lane];
    uint32_t p4 = hu[((size_t)(uint32_t)c4 << 6) + lane];
    uint32_t p5 = hu[((size_t)(uint32_t)c5 << 6) + lane];
    uint32_t p6 = hu[((size_t)(uint32_t)c6 << 6) + lane];
    uint32_t p7 = hu[((size_t)(uint32_t)c7 << 6) + lane];
    ax += bf_lo(p0) + bf_lo(p1) + bf_lo(p2) + bf_lo(p3)
        + bf_lo(p4) + bf_lo(p5) + bf_lo(p6) + bf_lo(p7);
    ay += bf_hi(p0) + bf_hi(p1) + bf_hi(p2) + bf_hi(p3)
        + bf_hi(p4) + bf_hi(p5) + bf_hi(p6) + bf_hi(p7);
  }
  for (; i + 4 <= cnt; i += 4) {
    int c0 = cp[i], c1 = cp[i + 1], c2 = cp[i + 2], c3 = cp[i + 3];
    uint32_t p0 = hu[((size_t)(uint32_t)c0 << 6) + lane];
    uint32_t p1 = hu[((size_t)(uint32_t)c1 << 6) + lane];
    uint32_t p2 = hu[((size_t)(uint32_t)c2 << 6) + lane];
    uint32_t p3 = hu[((size_t)(uint32_t)c3 << 6) + lane];
    ax += bf_lo(p0) + bf_lo(p1) + bf_lo(p2) + bf_lo(p3);
    ay += bf_hi(p0) + bf_hi(p1) + bf_hi(p2) + bf_hi(p3);
  }
  for (; i < cnt; ++i) {
    int c = cp[i];
    uint32_t p = hu[((size_t)(uint32_t)c << 6) + lane];
    ax += bf_lo(p);
    ay += bf_hi(p);
  }
  float di = dis[wid];
  int p = (lane & 31) | ((lane & 32) << 1);
  float* orow = out + (size_t)wid * 128;
  __builtin_nontemporal_store(di * ax, &orow[p]);
  __builtin_nontemporal_store(di * ay, &orow[p + 32]);
}

// ---- fallback path (small workspace): count -> dis -> per-edge atomics ----
__global__ void k_count(const int* __restrict__ rows, int E, int* __restrict__ deg) {
  int e = blockIdx.x * blockDim.x + threadIdx.x;
  if (e < E) atomicAdd(&deg[rows[e]], 1);
}

__global__ void k_dis(const int* __restrict__ deg, float* __restrict__ dis, int N) {
  int i = blockIdx.x * blockDim.x + threadIdx.x;
  if (i < N) dis[i] = rsqrtf((float)(deg[i] + 1));
}

__launch_bounds__(256)
__global__ void k_selfinit(const uint32_t* __restrict__ hu, const float* __restrict__ dis,
                           float* __restrict__ out, int N) {
  int wid = blockIdx.x * 4 + (threadIdx.x >> 6);
  int lane = threadIdx.x & 63;
  if (wid >= N) return;
  float di = dis[wid];
  uint32_t p = hu[(size_t)wid * 64 + lane];
  int pc = (lane & 31) | ((lane & 32) << 1);
  out[(size_t)wid * 128 + pc] = di * bf_lo(p);
  out[(size_t)wid * 128 + pc + 32] = di * bf_hi(p);
}

__launch_bounds__(256)
__global__ void k_edge_atomic(const int* __restrict__ rows, const int* __restrict__ cols, int E,
                              const uint32_t* __restrict__ hu, const float* __restrict__ dis,
                              float* __restrict__ out) {
  int wid = blockIdx.x * 4 + (threadIdx.x >> 6);
  int lane = threadIdx.x & 63;
  if (wid >= E) return;
  int r = rows[wid], c = cols[wid];
  float w = dis[r];  // hu'[c] already carries dis[c]
  uint32_t p = hu[(size_t)c * 64 + lane];
  int pc = (lane & 31) | ((lane & 32) << 1);
  atomicAdd(&out[(size_t)r * 128 + pc], w * bf_lo(p));
  atomicAdd(&out[(size_t)r * 128 + pc + 32], w * bf_hi(p));
}

extern "C" void kernel_launch(void* const* d_in, const int* in_sizes, int n_in,
                              void* d_out, int out_size, void* d_ws, size_t ws_size,
                              hipStream_t stream) {
  const float* x    = (const float*)d_in[0];
  const int*   ei   = (const int*)d_in[1];
  const float* W    = (const float*)d_in[2];
  const float* bias = (const float*)d_in[3];
  float* out = (float*)d_out;

  const int N = in_sizes[0] / 256;   // 100000
  const int E = in_sizes[1] / 2;     // 3200000
  const int NB = (N + RB - 1) / RB;  // 196 buckets of 512 rows
  const int* rows = ei;
  const int* cols = ei + E;

  // workspace layout (256B aligned slices)
  size_t off = 0;
  auto alloc = [&](size_t bytes) -> void* {
    void* p = (char*)d_ws + off;
    off += (bytes + 255) & ~(size_t)255;
    return p;
  };
  uint32_t* hu    = (uint32_t*)alloc((size_t)N * 64 * 4);  // bf16-packed dis*h
  float*    dis   = (float*)alloc((size_t)N * 4);
  int*      deg   = (int*)alloc((size_t)N * 4);            // fallback only
  uint16_t* wbf   = (uint16_t*)alloc(32768 * 2);           // bf16 W, [col][k]
  int*      bcnt  = (int*)alloc((size_t)NBMAX * 4);
  int*      gbase = (int*)alloc((size_t)NBMAX * 4);
  int*      gcur  = (int*)alloc((size_t)NBMAX * 4);
  int*      offs  = (int*)alloc((size_t)N * 4);
  size_t small_end = off;
  uint32_t* temp  = (uint32_t*)alloc((size_t)E * 4);
  int*      csr   = (int*)alloc((size_t)E * 4);
  bool full = (off <= ws_size);
  bool atomic_ok = (small_end <= ws_size);

  k_wcast<<<128, 256, 0, stream>>>(W, wbf);

  if (full) {
    hipMemsetAsync(bcnt, 0, (size_t)NBMAX * 4, stream);
    k_bhist<<<512, 256, 0, stream>>>(rows, E, NB, bcnt);
    k_scanb<<<1, 1024, 0, stream>>>(bcnt, NB, gbase, gcur);
    k_part<<<(E + CHUNK - 1) / CHUNK, 1024, 0, stream>>>(rows, cols, E, NB, gcur, temp);
    k_csr_build<<<NB, 1024, 0, stream>>>(gbase, bcnt, temp, N, offs, dis, csr);
    k_gemm<<<(N + 63) / 64, 256, 0, stream>>>(x, wbf, bias, dis, hu, N);
    k_aggregate<<<(N + 3) / 4, 256, 0, stream>>>(hu, dis, offs, csr, out, N, E);
  } else if (atomic_ok) {
    hipMemsetAsync(deg, 0, (size_t)N * 4, stream);
    k_count<<<(E + 255) / 256, 256, 0, stream>>>(rows, E, deg);
    k_dis<<<(N + 255) / 256, 256, 0, stream>>>(deg, dis, N);
    k_gemm<<<(N + 63) / 64, 256, 0, stream>>>(x, wbf, bias, dis, hu, N);
    k_selfinit<<<(N + 3) / 4, 256, 0, stream>>>(hu, dis, out, N);
    k_edge_atomic<<<(E + 3) / 4, 256, 0, stream>>>(rows, cols, E, hu, dis, out);
  }
}

// Round 11
// 224.359 us; speedup vs baseline: 1.0277x; 1.0277x over previous
//
#include <hip/hip_runtime.h>
#include <hip/hip_bf16.h>
#include <stdint.h>

// GCN layer: out = D^-1/2 (A+I) D^-1/2 (x W + b)
// N=100000 nodes, E=3.2M edges, 256 -> 128 features.
// Pipeline: W pre-cast to bf16 [col][k] -> bucket histogram/scan -> LDS-staged
// partition (512 rows/bucket, burst writes) -> per-bucket CSR build (1024 thr,
// also produces deg -> dis) -> bf16 MFMA GEMM (512 thr / M-tile 128, 4 waves/
// SIMD, stores hu' = bf16(dis*h)) -> wave-per-node gather, scalar addressing,
// 8 gathers in flight (measured at the L3 random-fetch ceiling ~4 TB/s).

#define RB    512      // rows per bucket
#define RBSH  9
#define NBMAX 256      // >= NB = ceil(100000/512) = 196
#define CHUNK 12288    // edges per partition block (LDS sorted array = 48 KB)

typedef __attribute__((ext_vector_type(8))) short short8v;   // 8 bf16
typedef __attribute__((ext_vector_type(16))) float f32x16;

__device__ __forceinline__ float bf_lo(uint32_t p) { return __uint_as_float(p << 16); }
__device__ __forceinline__ float bf_hi(uint32_t p) { return __uint_as_float(p & 0xffff0000u); }

__device__ __forceinline__ uint32_t f2bf(float f) {
  uint32_t u = __float_as_uint(f);
  return (u + 0x7fffu + ((u >> 16) & 1u)) >> 16;  // RNE
}

// HW pack-convert: (lo, hi) -> (bf16(hi)<<16)|bf16(lo), RNE via v_cvt_pk_bf16_f32
__device__ __forceinline__ uint32_t cvt_pk(float lo, float hi) {
  __hip_bfloat162 b = __float22bfloat162_rn(float2{lo, hi});
  union { __hip_bfloat162 b; uint32_t u; } cv;
  cv.b = b;
  return cv.u;
}

// ---- W cast: wbf[col*256 + k] = bf16(W[k*128 + col]) ----
__global__ void k_wcast(const float* __restrict__ W, uint16_t* __restrict__ wbf) {
  int t = blockIdx.x * 256 + threadIdx.x;   // 32768 total
  int col = t >> 8, k = t & 255;
  wbf[t] = (uint16_t)f2bf(W[k * 128 + col]);
}

// ---- bucket histogram (LDS-staged, few global atomics) ----
__launch_bounds__(256)
__global__ void k_bhist(const int* __restrict__ rows, int E, int NB,
                        int* __restrict__ bcnt) {
  __shared__ int h[NBMAX];
  int tid = threadIdx.x;
  for (int i = tid; i < NBMAX; i += 256) h[i] = 0;
  __syncthreads();
  int stride = gridDim.x * 256;
  for (int e = blockIdx.x * 256 + tid; e < E; e += stride)
    atomicAdd(&h[rows[e] >> RBSH], 1);
  __syncthreads();
  for (int b = tid; b < NB; b += 256)
    if (h[b]) atomicAdd(&bcnt[b], h[b]);
}

// ---- exclusive scan of bucket counts (single block, n <= 2048) ----
__global__ void k_scanb(const int* __restrict__ bcnt, int n,
                        int* __restrict__ gbase, int* __restrict__ gcur) {
  __shared__ int s[2048];
  int t = threadIdx.x;  // 1024 threads
  int v0 = (t < n) ? bcnt[t] : 0;
  int v1 = (t + 1024 < n) ? bcnt[t + 1024] : 0;
  s[t] = v0; s[t + 1024] = v1;
  __syncthreads();
  for (int d = 1; d < 2048; d <<= 1) {
    int a0 = (t >= d) ? s[t - d] : 0;
    int a1 = s[t + 1024 - d];
    __syncthreads();
    s[t] += a0; s[t + 1024] += a1;
    __syncthreads();
  }
  if (t < n)        { int e = s[t] - v0;        gbase[t] = e;        gcur[t] = e; }
  if (t + 1024 < n) { int e = s[t + 1024] - v1; gbase[t + 1024] = e; gcur[t + 1024] = e; }
}

// ---- LDS-staged partition: chunk -> bucket-sorted runs -> burst copy-out ----
__launch_bounds__(1024)
__global__ void k_part(const int* __restrict__ rows, const int* __restrict__ cols,
                       int E, int NB, int* __restrict__ gcur,
                       uint32_t* __restrict__ temp) {
  __shared__ uint32_t sorted[CHUNK];  // 48 KB
  __shared__ int hist[NBMAX];
  __shared__ int scanv[NBMAX];
  __shared__ int res[NBMAX];
  int tid = threadIdx.x;
  int base = blockIdx.x * CHUNK;
  int cnt = min(CHUNK, E - base);

  for (int i = tid; i < NBMAX; i += 1024) hist[i] = 0;
  __syncthreads();
  for (int i = tid; i < cnt; i += 1024)
    atomicAdd(&hist[rows[base + i] >> RBSH], 1);
  __syncthreads();
  if (tid < NBMAX) scanv[tid] = hist[tid];
  __syncthreads();
  for (int d = 1; d < NBMAX; d <<= 1) {
    int v = 0;
    if (tid < NBMAX && tid >= d) v = scanv[tid - d];
    __syncthreads();
    if (tid < NBMAX) scanv[tid] += v;
    __syncthreads();
  }
  if (tid < NB) {
    int c = hist[tid];
    res[tid] = c ? atomicAdd(&gcur[tid], c) : 0;  // one reservation per bucket
    hist[tid] = scanv[tid] - c;                   // lbase -> cursor
  }
  __syncthreads();
  for (int i = tid; i < cnt; i += 1024) {
    int r = rows[base + i];
    int c = cols[base + i];
    int b = r >> RBSH;
    int p = atomicAdd(&hist[b], 1);
    sorted[p] = ((uint32_t)(r & (RB - 1)) << 17) | (uint32_t)c;
  }
  __syncthreads();
  int wv = tid >> 6, lane = tid & 63;
  for (int b = wv; b < NB; b += 16) {   // wave-cooperative contiguous run copy
    int st = b ? scanv[b - 1] : 0;
    int en = scanv[b];
    int gb = res[b];
    for (int j = st + lane; j < en; j += 64)
      temp[gb + (j - st)] = sorted[j];
  }
}

// ---- per-bucket CSR build (1024 thr); also emits deg -> dis ----
__launch_bounds__(1024)
__global__ void k_csr_build(const int* __restrict__ gbase, const int* __restrict__ bcnt,
                            const uint32_t* __restrict__ temp, int N,
                            int* __restrict__ offs, float* __restrict__ dis,
                            int* __restrict__ csr) {
  __shared__ int cnt[RB];   // per-node count -> cursor
  __shared__ int S[256];
  int b = blockIdx.x;
  int tid = threadIdx.x;
  int base = gbase[b];
  int cb = bcnt[b];

  if (tid < RB) cnt[tid] = 0;
  __syncthreads();
  for (int i = tid; i < cb; i += 1024)
    atomicAdd(&cnt[temp[base + i] >> 17], 1);
  __syncthreads();
  int a0 = 0, a1 = 0, ex0 = 0;
  if (tid < 256) {
    a0 = cnt[2 * tid]; a1 = cnt[2 * tid + 1];
    S[tid] = a0 + a1;
  }
  __syncthreads();
  for (int d = 1; d < 256; d <<= 1) {
    int v = 0;
    if (tid < 256 && tid >= d) v = S[tid - d];
    __syncthreads();
    if (tid < 256) S[tid] += v;
    __syncthreads();
  }
  if (tid < 256) {
    ex0 = S[tid] - (a0 + a1);
    int r0 = b * RB + 2 * tid;
    if (r0 < N)     { dis[r0]     = rsqrtf((float)(a0 + 1)); offs[r0]     = base + ex0; }
    if (r0 + 1 < N) { dis[r0 + 1] = rsqrtf((float)(a1 + 1)); offs[r0 + 1] = base + ex0 + a0; }
  }
  __syncthreads();
  if (tid < 256) {
    cnt[2 * tid]     = ex0;       // cursor start
    cnt[2 * tid + 1] = ex0 + a0;
  }
  __syncthreads();
  for (int i = tid; i < cb; i += 1024) {
    uint32_t pk = temp[base + i];
    int lrow = pk >> 17;
    int c = (int)(pk & 0x1FFFF);
    int p = atomicAdd(&cnt[lrow], 1);
    csr[base + p] = c;
  }
}

// ---- bf16 MFMA GEMM: h = x W + b; store hu[m*64+j] = bf16(dis[m]*h) pair ----
// Block: 512 thr = 8 waves, M-tile 128, all 128 cols -> 64 KB W-LDS amortized
// at 16 waves/CU (4/SIMD). Wave w: rows [32(w&3),+32), cols [64(w>>2),+64) as
// two 32x32 tiles. A-frags straight from global (x rows used once, v_cvt_pk);
// W in LDS bf16 [col][k], 16B-slot XOR swizzle => conflict-free b128.
// hu dword j packs feats (p, p+32), p = (j&31) | ((j&32)<<1).
__launch_bounds__(512)
__global__ void k_gemm(const float* __restrict__ x, const uint16_t* __restrict__ wbf,
                       const float* __restrict__ bias, const float* __restrict__ dis,
                       uint32_t* __restrict__ hu, int M) {
  __shared__ uint16_t wlds[32768];  // 64 KB
  int tid = threadIdx.x;
  {
    const uint4* src = (const uint4*)wbf;
#pragma unroll
    for (int i = 0; i < 8; ++i) {      // 8 * 512 = 4096 chunks = full 64 KB
      int chunk = i * 512 + tid;       // 16B chunks: col = chunk>>5, slot = chunk&31
      uint4 v = src[chunk];
      int col = chunk >> 5, s = chunk & 31;
      int sp = s ^ (col & 31);
      *(uint4*)&wlds[col * 256 + sp * 8] = v;
    }
  }
  int w = tid >> 6, l = tid & 63;
  int lr = l & 31, g = l >> 5;
  int row = blockIdx.x * 128 + (w & 3) * 32 + lr;
  int c0 = (w >> 2) * 64;
  bool valid = row < M;
  const float* xrow = x + (size_t)row * 256;
  f32x16 acc0 = {}, acc1 = {};
  __syncthreads();
#pragma unroll
  for (int kt = 0; kt < 16; ++kt) {
    int k0 = kt * 16 + g * 8;          // lane's 8 contiguous k
    float4 f0 = make_float4(0.f, 0.f, 0.f, 0.f), f1 = f0;
    if (valid) {
      f0 = *(const float4*)(xrow + k0);
      f1 = *(const float4*)(xrow + k0 + 4);
    }
    union { uint32_t u[4]; short8v v; } av;
    av.u[0] = cvt_pk(f0.x, f0.y);
    av.u[1] = cvt_pk(f0.z, f0.w);
    av.u[2] = cvt_pk(f1.x, f1.y);
    av.u[3] = cvt_pk(f1.z, f1.w);
    int sp = (kt * 2 + g) ^ lr;        // swizzled 16B slot
    short8v b0 = *(short8v*)&wlds[(c0 + lr) * 256 + sp * 8];
    short8v b1 = *(short8v*)&wlds[(c0 + 32 + lr) * 256 + sp * 8];
    acc0 = __builtin_amdgcn_mfma_f32_32x32x16_bf16(av.v, b0, acc0, 0, 0, 0);
    acc1 = __builtin_amdgcn_mfma_f32_32x32x16_bf16(av.v, b1, acc1, 0, 0, 0);
  }
  int j = lr + (w >> 2) * 32;          // hu pair index
  int p = c0 + lr;                     // actual feature col of tile0
  float bl = bias[p], bh = bias[p + 32];
#pragma unroll
  for (int r = 0; r < 16; ++r) {
    int mrow = blockIdx.x * 128 + (w & 3) * 32 + (r & 3) + 8 * (r >> 2) + 4 * g;
    if (mrow < M) {
      float di = dis[mrow];
      hu[(size_t)mrow * 64 + j] = cvt_pk(di * (acc0[r] + bl), di * (acc1[r] + bh));
    }
  }
}

// ---- aggregation: wave per node, scalar addressing, 8 gathers in flight ----
// e/end readfirstlane'd -> csr reads on the scalar pipe, hu row base SGPR +
// loop-invariant lane offset. Measured at the L3 random-fetch ceiling.
__launch_bounds__(256)
__global__ void k_aggregate(const uint32_t* __restrict__ hu, const float* __restrict__ dis,
                            const int* __restrict__ offs, const int* __restrict__ csr,
                            float* __restrict__ out, int N, int E) {
  int wid = blockIdx.x * 4 + (threadIdx.x >> 6);
  int lane = threadIdx.x & 63;
  if (wid >= N) return;
  int e0  = __builtin_amdgcn_readfirstlane(offs[wid]);
  int end = __builtin_amdgcn_readfirstlane((wid + 1 < N) ? offs[wid + 1] : E);
  int cnt = end - e0;
  const int* cp = csr + e0;                       // uniform (SGPR) base
  const uint32_t* hrow = hu + ((size_t)(uint32_t)wid << 6);
  uint32_t ps = hrow[lane];
  float ax = bf_lo(ps);   // self loop: hu' already has dis folded in
  float ay = bf_hi(ps);
  int i = 0;
  for (; i + 8 <= cnt; i += 8) {                  // 8 independent gathers in flight
    int c0 = cp[i],     c1 = cp[i + 1], c2 = cp[i + 2], c3 = cp[i + 3];
    int c4 = cp[i + 4], c5 = cp[i + 5], c6 = cp[i + 6], c7 = cp[i + 7];
    uint32_t p0 = hu[((size_t)(uint32_t)c0 << 6) + lane];
    uint32_t p1 = hu[((size_t)(uint32_t)c1 << 6) + lane];
    uint32_t p2 = hu[((size_t)(uint32_t)c2 << 6) + lane];
    uint32_t p3 = hu[((size_t)(uint32_t)c3 << 6) + lane];
    uint32_t p4 = hu[((size_t)(uint32_t)c4 << 6) + lane];
    uint32_t p5 = hu[((size_t)(uint32_t)c5 << 6) + lane];
    uint32_t p6 = hu[((size_t)(uint32_t)c6 << 6) + lane];
    uint32_t p7 = hu[((size_t)(uint32_t)c7 << 6) + lane];
    ax += bf_lo(p0) + bf_lo(p1) + bf_lo(p2) + bf_lo(p3)
        + bf_lo(p4) + bf_lo(p5) + bf_lo(p6) + bf_lo(p7);
    ay += bf_hi(p0) + bf_hi(p1) + bf_hi(p2) + bf_hi(p3)
        + bf_hi(p4) + bf_hi(p5) + bf_hi(p6) + bf_hi(p7);
  }
  for (; i + 4 <= cnt; i += 4) {
    int c0 = cp[i], c1 = cp[i + 1], c2 = cp[i + 2], c3 = cp[i + 3];
    uint32_t p0 = hu[((size_t)(uint32_t)c0 << 6) + lane];
    uint32_t p1 = hu[((size_t)(uint32_t)c1 << 6) + lane];
    uint32_t p2 = hu[((size_t)(uint32_t)c2 << 6) + lane];
    uint32_t p3 = hu[((size_t)(uint32_t)c3 << 6) + lane];
    ax += bf_lo(p0) + bf_lo(p1) + bf_lo(p2) + bf_lo(p3);
    ay += bf_hi(p0) + bf_hi(p1) + bf_hi(p2) + bf_hi(p3);
  }
  for (; i < cnt; ++i) {
    int c = cp[i];
    uint32_t p = hu[((size_t)(uint32_t)c << 6) + lane];
    ax += bf_lo(p);
    ay += bf_hi(p);
  }
  float di = dis[wid];
  int p = (lane & 31) | ((lane & 32) << 1);
  float* orow = out + (size_t)wid * 128;
  __builtin_nontemporal_store(di * ax, &orow[p]);
  __builtin_nontemporal_store(di * ay, &orow[p + 32]);
}

// ---- fallback path (small workspace): count -> dis -> per-edge atomics ----
__global__ void k_count(const int* __restrict__ rows, int E, int* __restrict__ deg) {
  int e = blockIdx.x * blockDim.x + threadIdx.x;
  if (e < E) atomicAdd(&deg[rows[e]], 1);
}

__global__ void k_dis(const int* __restrict__ deg, float* __restrict__ dis, int N) {
  int i = blockIdx.x * blockDim.x + threadIdx.x;
  if (i < N) dis[i] = rsqrtf((float)(deg[i] + 1));
}

__launch_bounds__(256)
__global__ void k_selfinit(const uint32_t* __restrict__ hu, const float* __restrict__ dis,
                           float* __restrict__ out, int N) {
  int wid = blockIdx.x * 4 + (threadIdx.x >> 6);
  int lane = threadIdx.x & 63;
  if (wid >= N) return;
  float di = dis[wid];
  uint32_t p = hu[(size_t)wid * 64 + lane];
  int pc = (lane & 31) | ((lane & 32) << 1);
  out[(size_t)wid * 128 + pc] = di * bf_lo(p);
  out[(size_t)wid * 128 + pc + 32] = di * bf_hi(p);
}

__launch_bounds__(256)
__global__ void k_edge_atomic(const int* __restrict__ rows, const int* __restrict__ cols, int E,
                              const uint32_t* __restrict__ hu, const float* __restrict__ dis,
                              float* __restrict__ out) {
  int wid = blockIdx.x * 4 + (threadIdx.x >> 6);
  int lane = threadIdx.x & 63;
  if (wid >= E) return;
  int r = rows[wid], c = cols[wid];
  float w = dis[r];  // hu'[c] already carries dis[c]
  uint32_t p = hu[(size_t)c * 64 + lane];
  int pc = (lane & 31) | ((lane & 32) << 1);
  atomicAdd(&out[(size_t)r * 128 + pc], w * bf_lo(p));
  atomicAdd(&out[(size_t)r * 128 + pc + 32], w * bf_hi(p));
}

extern "C" void kernel_launch(void* const* d_in, const int* in_sizes, int n_in,
                              void* d_out, int out_size, void* d_ws, size_t ws_size,
                              hipStream_t stream) {
  const float* x    = (const float*)d_in[0];
  const int*   ei   = (const int*)d_in[1];
  const float* W    = (const float*)d_in[2];
  const float* bias = (const float*)d_in[3];
  float* out = (float*)d_out;

  const int N = in_sizes[0] / 256;   // 100000
  const int E = in_sizes[1] / 2;     // 3200000
  const int NB = (N + RB - 1) / RB;  // 196 buckets of 512 rows
  const int* rows = ei;
  const int* cols = ei + E;

  // workspace layout (256B aligned slices)
  size_t off = 0;
  auto alloc = [&](size_t bytes) -> void* {
    void* p = (char*)d_ws + off;
    off += (bytes + 255) & ~(size_t)255;
    return p;
  };
  uint32_t* hu    = (uint32_t*)alloc((size_t)N * 64 * 4);  // bf16-packed dis*h
  float*    dis   = (float*)alloc((size_t)N * 4);
  int*      deg   = (int*)alloc((size_t)N * 4);            // fallback only
  uint16_t* wbf   = (uint16_t*)alloc(32768 * 2);           // bf16 W, [col][k]
  int*      bcnt  = (int*)alloc((size_t)NBMAX * 4);
  int*      gbase = (int*)alloc((size_t)NBMAX * 4);
  int*      gcur  = (int*)alloc((size_t)NBMAX * 4);
  int*      offs  = (int*)alloc((size_t)N * 4);
  size_t small_end = off;
  uint32_t* temp  = (uint32_t*)alloc((size_t)E * 4);
  int*      csr   = (int*)alloc((size_t)E * 4);
  bool full = (off <= ws_size);
  bool atomic_ok = (small_end <= ws_size);

  k_wcast<<<128, 256, 0, stream>>>(W, wbf);

  if (full) {
    hipMemsetAsync(bcnt, 0, (size_t)NBMAX * 4, stream);
    k_bhist<<<512, 256, 0, stream>>>(rows, E, NB, bcnt);
    k_scanb<<<1, 1024, 0, stream>>>(bcnt, NB, gbase, gcur);
    k_part<<<(E + CHUNK - 1) / CHUNK, 1024, 0, stream>>>(rows, cols, E, NB, gcur, temp);
    k_csr_build<<<NB, 1024, 0, stream>>>(gbase, bcnt, temp, N, offs, dis, csr);
    k_gemm<<<(N + 127) / 128, 512, 0, stream>>>(x, wbf, bias, dis, hu, N);
    k_aggregate<<<(N + 3) / 4, 256, 0, stream>>>(hu, dis, offs, csr, out, N, E);
  } else if (atomic_ok) {
    hipMemsetAsync(deg, 0, (size_t)N * 4, stream);
    k_count<<<(E + 255) / 256, 256, 0, stream>>>(rows, E, deg);
    k_dis<<<(N + 255) / 256, 256, 0, stream>>>(deg, dis, N);
    k_gemm<<<(N + 127) / 128, 512, 0, stream>>>(x, wbf, bias, dis, hu, N);
    k_selfinit<<<(N + 3) / 4, 256, 0, stream>>>(hu, dis, out, N);
    k_edge_atomic<<<(E + 3) / 4, 256, 0, stream>>>(rows, cols, E, hu, dis, out);
  }
}

// Round 12
// 199.548 us; speedup vs baseline: 1.1555x; 1.1243x over previous
//
#include <hip/hip_runtime.h>
#include <hip/hip_bf16.h>
#include <stdint.h>

// GCN layer: out = D^-1/2 (A+I) D^-1/2 (x W + b)
// N=100000 nodes, E=3.2M edges, 256 -> 128 features.
// Pipeline: W pre-cast to bf16 [col][k] (+ gcur init) -> LDS-staged partition
// into FIXED-CAPACITY buckets (512 rows, 20480 edges cap = +32 sigma; no
// histogram pre-pass) -> per-bucket CSR build (1024 thr, emits deg -> dis,
// offs, cnts) -> bf16 MFMA GEMM (512 thr / M-tile 128, stores hu'=bf16(dis*h))
// -> wave-per-node gather, scalar addressing, 8 gathers in flight
// (measured at the L3 random-fetch ceiling ~4 TB/s).

#define RB     512     // rows per bucket
#define RBSH   9
#define NBMAX  256     // >= NB = ceil(100000/512) = 196
#define CHUNK  12288   // edges per partition block (LDS sorted array = 48 KB)
#define BSTRIDE 20480  // fixed bucket capacity (exp 16327, sigma 127 -> +32s)

typedef __attribute__((ext_vector_type(8))) short short8v;   // 8 bf16
typedef __attribute__((ext_vector_type(16))) float f32x16;

__device__ __forceinline__ float bf_lo(uint32_t p) { return __uint_as_float(p << 16); }
__device__ __forceinline__ float bf_hi(uint32_t p) { return __uint_as_float(p & 0xffff0000u); }

__device__ __forceinline__ uint32_t f2bf(float f) {
  uint32_t u = __float_as_uint(f);
  return (u + 0x7fffu + ((u >> 16) & 1u)) >> 16;  // RNE
}

// HW pack-convert: (lo, hi) -> (bf16(hi)<<16)|bf16(lo), RNE via v_cvt_pk_bf16_f32
__device__ __forceinline__ uint32_t cvt_pk(float lo, float hi) {
  __hip_bfloat162 b = __float22bfloat162_rn(float2{lo, hi});
  union { __hip_bfloat162 b; uint32_t u; } cv;
  cv.b = b;
  return cv.u;
}

// ---- W cast: wbf[col*256 + k] = bf16(W[k*128 + col]); block 0 inits gcur ----
__global__ void k_wcast(const float* __restrict__ W, uint16_t* __restrict__ wbf,
                        int* __restrict__ gcur, int NB) {
  int tid = threadIdx.x;
  if (blockIdx.x == 0 && tid < NB) gcur[tid] = tid * BSTRIDE;
  int t = blockIdx.x * 256 + tid;   // 32768 total
  int col = t >> 8, k = t & 255;
  wbf[t] = (uint16_t)f2bf(W[k * 128 + col]);
}

// ---- LDS-staged partition: chunk -> bucket-sorted runs -> burst copy-out ----
__launch_bounds__(1024)
__global__ void k_part(const int* __restrict__ rows, const int* __restrict__ cols,
                       int E, int NB, int* __restrict__ gcur,
                       uint32_t* __restrict__ temp) {
  __shared__ uint32_t sorted[CHUNK];  // 48 KB
  __shared__ int hist[NBMAX];
  __shared__ int scanv[NBMAX];
  __shared__ int res[NBMAX];
  int tid = threadIdx.x;
  int base = blockIdx.x * CHUNK;
  int cnt = min(CHUNK, E - base);

  for (int i = tid; i < NBMAX; i += 1024) hist[i] = 0;
  __syncthreads();
  for (int i = tid; i < cnt; i += 1024)
    atomicAdd(&hist[rows[base + i] >> RBSH], 1);
  __syncthreads();
  if (tid < NBMAX) scanv[tid] = hist[tid];
  __syncthreads();
  for (int d = 1; d < NBMAX; d <<= 1) {
    int v = 0;
    if (tid < NBMAX && tid >= d) v = scanv[tid - d];
    __syncthreads();
    if (tid < NBMAX) scanv[tid] += v;
    __syncthreads();
  }
  if (tid < NB) {
    int c = hist[tid];
    res[tid] = c ? atomicAdd(&gcur[tid], c) : 0;  // one reservation per bucket
    hist[tid] = scanv[tid] - c;                   // lbase -> cursor
  }
  __syncthreads();
  for (int i = tid; i < cnt; i += 1024) {
    int r = rows[base + i];
    int c = cols[base + i];
    int b = r >> RBSH;
    int p = atomicAdd(&hist[b], 1);
    sorted[p] = ((uint32_t)(r & (RB - 1)) << 17) | (uint32_t)c;
  }
  __syncthreads();
  int wv = tid >> 6, lane = tid & 63;
  for (int b = wv; b < NB; b += 16) {   // wave-cooperative contiguous run copy
    int st = b ? scanv[b - 1] : 0;
    int en = scanv[b];
    int gb = res[b];
    for (int j = st + lane; j < en; j += 64)
      temp[gb + (j - st)] = sorted[j];
  }
}

// ---- per-bucket CSR build (1024 thr); emits deg -> dis, offs, cnts ----
__launch_bounds__(1024)
__global__ void k_csr_build(const int* __restrict__ gcur,
                            const uint32_t* __restrict__ temp, int N,
                            int* __restrict__ offs, int* __restrict__ cnts,
                            float* __restrict__ dis, int* __restrict__ csr) {
  __shared__ int cnt[RB];   // per-node count -> cursor
  __shared__ int S[256];
  int b = blockIdx.x;
  int tid = threadIdx.x;
  int base = b * BSTRIDE;
  int cb = gcur[b] - base;

  if (tid < RB) cnt[tid] = 0;
  __syncthreads();
  for (int i = tid; i < cb; i += 1024)
    atomicAdd(&cnt[temp[base + i] >> 17], 1);
  __syncthreads();
  int a0 = 0, a1 = 0, ex0 = 0;
  if (tid < 256) {
    a0 = cnt[2 * tid]; a1 = cnt[2 * tid + 1];
    S[tid] = a0 + a1;
  }
  __syncthreads();
  for (int d = 1; d < 256; d <<= 1) {
    int v = 0;
    if (tid < 256 && tid >= d) v = S[tid - d];
    __syncthreads();
    if (tid < 256) S[tid] += v;
    __syncthreads();
  }
  if (tid < 256) {
    ex0 = S[tid] - (a0 + a1);
    int r0 = b * RB + 2 * tid;
    if (r0 < N) {
      dis[r0] = rsqrtf((float)(a0 + 1));
      offs[r0] = base + ex0;
      cnts[r0] = a0;
    }
    if (r0 + 1 < N) {
      dis[r0 + 1] = rsqrtf((float)(a1 + 1));
      offs[r0 + 1] = base + ex0 + a0;
      cnts[r0 + 1] = a1;
    }
  }
  __syncthreads();
  if (tid < 256) {
    cnt[2 * tid]     = ex0;       // cursor start
    cnt[2 * tid + 1] = ex0 + a0;
  }
  __syncthreads();
  for (int i = tid; i < cb; i += 1024) {
    uint32_t pk = temp[base + i];
    int lrow = pk >> 17;
    int c = (int)(pk & 0x1FFFF);
    int p = atomicAdd(&cnt[lrow], 1);
    csr[base + p] = c;
  }
}

// ---- bf16 MFMA GEMM: h = x W + b; store hu[m*64+j] = bf16(dis[m]*h) pair ----
// Block: 512 thr = 8 waves, M-tile 128, all 128 cols -> 64 KB W-LDS amortized
// at 16 waves/CU (4/SIMD). Wave w: rows [32(w&3),+32), cols [64(w>>2),+64) as
// two 32x32 tiles. A-frags straight from global (x rows used once, v_cvt_pk);
// W in LDS bf16 [col][k], 16B-slot XOR swizzle => conflict-free b128.
// hu dword j packs feats (p, p+32), p = (j&31) | ((j&32)<<1).
__launch_bounds__(512)
__global__ void k_gemm(const float* __restrict__ x, const uint16_t* __restrict__ wbf,
                       const float* __restrict__ bias, const float* __restrict__ dis,
                       uint32_t* __restrict__ hu, int M) {
  __shared__ uint16_t wlds[32768];  // 64 KB
  int tid = threadIdx.x;
  {
    const uint4* src = (const uint4*)wbf;
#pragma unroll
    for (int i = 0; i < 8; ++i) {      // 8 * 512 = 4096 chunks = full 64 KB
      int chunk = i * 512 + tid;       // 16B chunks: col = chunk>>5, slot = chunk&31
      uint4 v = src[chunk];
      int col = chunk >> 5, s = chunk & 31;
      int sp = s ^ (col & 31);
      *(uint4*)&wlds[col * 256 + sp * 8] = v;
    }
  }
  int w = tid >> 6, l = tid & 63;
  int lr = l & 31, g = l >> 5;
  int row = blockIdx.x * 128 + (w & 3) * 32 + lr;
  int c0 = (w >> 2) * 64;
  bool valid = row < M;
  const float* xrow = x + (size_t)row * 256;
  f32x16 acc0 = {}, acc1 = {};
  __syncthreads();
#pragma unroll
  for (int kt = 0; kt < 16; ++kt) {
    int k0 = kt * 16 + g * 8;          // lane's 8 contiguous k
    float4 f0 = make_float4(0.f, 0.f, 0.f, 0.f), f1 = f0;
    if (valid) {
      f0 = *(const float4*)(xrow + k0);
      f1 = *(const float4*)(xrow + k0 + 4);
    }
    union { uint32_t u[4]; short8v v; } av;
    av.u[0] = cvt_pk(f0.x, f0.y);
    av.u[1] = cvt_pk(f0.z, f0.w);
    av.u[2] = cvt_pk(f1.x, f1.y);
    av.u[3] = cvt_pk(f1.z, f1.w);
    int sp = (kt * 2 + g) ^ lr;        // swizzled 16B slot
    short8v b0 = *(short8v*)&wlds[(c0 + lr) * 256 + sp * 8];
    short8v b1 = *(short8v*)&wlds[(c0 + 32 + lr) * 256 + sp * 8];
    acc0 = __builtin_amdgcn_mfma_f32_32x32x16_bf16(av.v, b0, acc0, 0, 0, 0);
    acc1 = __builtin_amdgcn_mfma_f32_32x32x16_bf16(av.v, b1, acc1, 0, 0, 0);
  }
  int j = lr + (w >> 2) * 32;          // hu pair index
  int p = c0 + lr;                     // actual feature col of tile0
  float bl = bias[p], bh = bias[p + 32];
#pragma unroll
  for (int r = 0; r < 16; ++r) {
    int mrow = blockIdx.x * 128 + (w & 3) * 32 + (r & 3) + 8 * (r >> 2) + 4 * g;
    if (mrow < M) {
      float di = dis[mrow];
      hu[(size_t)mrow * 64 + j] = cvt_pk(di * (acc0[r] + bl), di * (acc1[r] + bh));
    }
  }
}

// ---- aggregation: wave per node, scalar addressing, 8 gathers in flight ----
// offs/cnts readfirstlane'd -> csr reads on the scalar pipe, hu row base SGPR
// + loop-invariant lane offset. Measured at the L3 random-fetch ceiling.
__launch_bounds__(256)
__global__ void k_aggregate(const uint32_t* __restrict__ hu, const float* __restrict__ dis,
                            const int* __restrict__ offs, const int* __restrict__ cnts,
                            const int* __restrict__ csr,
                            float* __restrict__ out, int N) {
  int wid = blockIdx.x * 4 + (threadIdx.x >> 6);
  int lane = threadIdx.x & 63;
  if (wid >= N) return;
  int e0  = __builtin_amdgcn_readfirstlane(offs[wid]);
  int cnt = __builtin_amdgcn_readfirstlane(cnts[wid]);
  const int* cp = csr + e0;                       // uniform (SGPR) base
  const uint32_t* hrow = hu + ((size_t)(uint32_t)wid << 6);
  uint32_t ps = hrow[lane];
  float ax = bf_lo(ps);   // self loop: hu' already has dis folded in
  float ay = bf_hi(ps);
  int i = 0;
  for (; i + 8 <= cnt; i += 8) {                  // 8 independent gathers in flight
    int c0 = cp[i],     c1 = cp[i + 1], c2 = cp[i + 2], c3 = cp[i + 3];
    int c4 = cp[i + 4], c5 = cp[i + 5], c6 = cp[i + 6], c7 = cp[i + 7];
    uint32_t p0 = hu[((size_t)(uint32_t)c0 << 6) + lane];
    uint32_t p1 = hu[((size_t)(uint32_t)c1 << 6) + lane];
    uint32_t p2 = hu[((size_t)(uint32_t)c2 << 6) + lane];
    uint32_t p3 = hu[((size_t)(uint32_t)c3 << 6) + lane];
    uint32_t p4 = hu[((size_t)(uint32_t)c4 << 6) + lane];
    uint32_t p5 = hu[((size_t)(uint32_t)c5 << 6) + lane];
    uint32_t p6 = hu[((size_t)(uint32_t)c6 << 6) + lane];
    uint32_t p7 = hu[((size_t)(uint32_t)c7 << 6) + lane];
    ax += bf_lo(p0) + bf_lo(p1) + bf_lo(p2) + bf_lo(p3)
        + bf_lo(p4) + bf_lo(p5) + bf_lo(p6) + bf_lo(p7);
    ay += bf_hi(p0) + bf_hi(p1) + bf_hi(p2) + bf_hi(p3)
        + bf_hi(p4) + bf_hi(p5) + bf_hi(p6) + bf_hi(p7);
  }
  for (; i + 4 <= cnt; i += 4) {
    int c0 = cp[i], c1 = cp[i + 1], c2 = cp[i + 2], c3 = cp[i + 3];
    uint32_t p0 = hu[((size_t)(uint32_t)c0 << 6) + lane];
    uint32_t p1 = hu[((size_t)(uint32_t)c1 << 6) + lane];
    uint32_t p2 = hu[((size_t)(uint32_t)c2 << 6) + lane];
    uint32_t p3 = hu[((size_t)(uint32_t)c3 << 6) + lane];
    ax += bf_lo(p0) + bf_lo(p1) + bf_lo(p2) + bf_lo(p3);
    ay += bf_hi(p0) + bf_hi(p1) + bf_hi(p2) + bf_hi(p3);
  }
  for (; i < cnt; ++i) {
    int c = cp[i];
    uint32_t p = hu[((size_t)(uint32_t)c << 6) + lane];
    ax += bf_lo(p);
    ay += bf_hi(p);
  }
  float di = dis[wid];
  int p = (lane & 31) | ((lane & 32) << 1);
  float* orow = out + (size_t)wid * 128;
  __builtin_nontemporal_store(di * ax, &orow[p]);
  __builtin_nontemporal_store(di * ay, &orow[p + 32]);
}

// ---- fallback path (small workspace): count -> dis -> per-edge atomics ----
__global__ void k_count(const int* __restrict__ rows, int E, int* __restrict__ deg) {
  int e = blockIdx.x * blockDim.x + threadIdx.x;
  if (e < E) atomicAdd(&deg[rows[e]], 1);
}

__global__ void k_dis(const int* __restrict__ deg, float* __restrict__ dis, int N) {
  int i = blockIdx.x * blockDim.x + threadIdx.x;
  if (i < N) dis[i] = rsqrtf((float)(deg[i] + 1));
}

__launch_bounds__(256)
__global__ void k_selfinit(const uint32_t* __restrict__ hu, const float* __restrict__ dis,
                           float* __restrict__ out, int N) {
  int wid = blockIdx.x * 4 + (threadIdx.x >> 6);
  int lane = threadIdx.x & 63;
  if (wid >= N) return;
  float di = dis[wid];
  uint32_t p = hu[(size_t)wid * 64 + lane];
  int pc = (lane & 31) | ((lane & 32) << 1);
  out[(size_t)wid * 128 + pc] = di * bf_lo(p);
  out[(size_t)wid * 128 + pc + 32] = di * bf_hi(p);
}

__launch_bounds__(256)
__global__ void k_edge_atomic(const int* __restrict__ rows, const int* __restrict__ cols, int E,
                              const uint32_t* __restrict__ hu, const float* __restrict__ dis,
                              float* __restrict__ out) {
  int wid = blockIdx.x * 4 + (threadIdx.x >> 6);
  int lane = threadIdx.x & 63;
  if (wid >= E) return;
  int r = rows[wid], c = cols[wid];
  float w = dis[r];  // hu'[c] already carries dis[c]
  uint32_t p = hu[(size_t)c * 64 + lane];
  int pc = (lane & 31) | ((lane & 32) << 1);
  atomicAdd(&out[(size_t)r * 128 + pc], w * bf_lo(p));
  atomicAdd(&out[(size_t)r * 128 + pc + 32], w * bf_hi(p));
}

extern "C" void kernel_launch(void* const* d_in, const int* in_sizes, int n_in,
                              void* d_out, int out_size, void* d_ws, size_t ws_size,
                              hipStream_t stream) {
  const float* x    = (const float*)d_in[0];
  const int*   ei   = (const int*)d_in[1];
  const float* W    = (const float*)d_in[2];
  const float* bias = (const float*)d_in[3];
  float* out = (float*)d_out;

  const int N = in_sizes[0] / 256;   // 100000
  const int E = in_sizes[1] / 2;     // 3200000
  const int NB = (N + RB - 1) / RB;  // 196 buckets of 512 rows
  const int* rows = ei;
  const int* cols = ei + E;

  // workspace layout (256B aligned slices)
  size_t off = 0;
  auto alloc = [&](size_t bytes) -> void* {
    void* p = (char*)d_ws + off;
    off += (bytes + 255) & ~(size_t)255;
    return p;
  };
  uint32_t* hu    = (uint32_t*)alloc((size_t)N * 64 * 4);  // bf16-packed dis*h
  float*    dis   = (float*)alloc((size_t)N * 4);
  int*      deg   = (int*)alloc((size_t)N * 4);            // fallback only
  uint16_t* wbf   = (uint16_t*)alloc(32768 * 2);           // bf16 W, [col][k]
  int*      gcur  = (int*)alloc((size_t)NBMAX * 4);
  int*      offs  = (int*)alloc((size_t)N * 4);
  int*      cnts  = (int*)alloc((size_t)N * 4);
  size_t small_end = off;
  uint32_t* temp  = (uint32_t*)alloc((size_t)NB * BSTRIDE * 4);
  int*      csr   = (int*)alloc((size_t)NB * BSTRIDE * 4);
  bool full = (off <= ws_size);
  bool atomic_ok = (small_end <= ws_size);

  k_wcast<<<128, 256, 0, stream>>>(W, wbf, gcur, NB);

  if (full) {
    k_part<<<(E + CHUNK - 1) / CHUNK, 1024, 0, stream>>>(rows, cols, E, NB, gcur, temp);
    k_csr_build<<<NB, 1024, 0, stream>>>(gcur, temp, N, offs, cnts, dis, csr);
    k_gemm<<<(N + 127) / 128, 512, 0, stream>>>(x, wbf, bias, dis, hu, N);
    k_aggregate<<<(N + 3) / 4, 256, 0, stream>>>(hu, dis, offs, cnts, csr, out, N);
  } else if (atomic_ok) {
    hipMemsetAsync(deg, 0, (size_t)N * 4, stream);
    k_count<<<(E + 255) / 256, 256, 0, stream>>>(rows, E, deg);
    k_dis<<<(N + 255) / 256, 256, 0, stream>>>(deg, dis, N);
    k_gemm<<<(N + 127) / 128, 512, 0, stream>>>(x, wbf, bias, dis, hu, N);
    k_selfinit<<<(N + 3) / 4, 256, 0, stream>>>(hu, dis, out, N);
    k_edge_atomic<<<(E + 3) / 4, 256, 0, stream>>>(rows, cols, E, hu, dis, out);
  }
}

// Round 13
// 195.584 us; speedup vs baseline: 1.1790x; 1.0203x over previous
//
#include <hip/hip_runtime.h>
#include <hip/hip_bf16.h>
#include <stdint.h>

// GCN layer: out = D^-1/2 (A+I) D^-1/2 (x W + b)
// N=100000 nodes, E=3.2M edges, 256 -> 128 features.
// Pipeline: W pre-cast to bf16 [col][k] (+ gcur init) -> LDS-staged partition
// into FIXED-CAPACITY buckets (512 rows, 20480 cap; int4-vectorized) ->
// per-bucket CSR build (1024 thr, uint4-vectorized; emits deg -> dis, offs,
// cnts) -> bf16 MFMA GEMM (512 thr / M-tile 128, stores hu'=bf16(dis*h)) ->
// wave-per-node gather, scalar addressing, 8 gathers in flight
// (measured at the L3 random-fetch ceiling ~4 TB/s).

#define RB     512     // rows per bucket
#define RBSH   9
#define NBMAX  256     // >= NB = ceil(100000/512) = 196
#define CHUNK  12288   // edges per partition block (LDS sorted array = 48 KB)
#define BSTRIDE 20480  // fixed bucket capacity (exp 16327, sigma 127 -> +32s)

typedef __attribute__((ext_vector_type(8))) short short8v;   // 8 bf16
typedef __attribute__((ext_vector_type(16))) float f32x16;

__device__ __forceinline__ float bf_lo(uint32_t p) { return __uint_as_float(p << 16); }
__device__ __forceinline__ float bf_hi(uint32_t p) { return __uint_as_float(p & 0xffff0000u); }

__device__ __forceinline__ uint32_t f2bf(float f) {
  uint32_t u = __float_as_uint(f);
  return (u + 0x7fffu + ((u >> 16) & 1u)) >> 16;  // RNE
}

// HW pack-convert: (lo, hi) -> (bf16(hi)<<16)|bf16(lo), RNE via v_cvt_pk_bf16_f32
__device__ __forceinline__ uint32_t cvt_pk(float lo, float hi) {
  __hip_bfloat162 b = __float22bfloat162_rn(float2{lo, hi});
  union { __hip_bfloat162 b; uint32_t u; } cv;
  cv.b = b;
  return cv.u;
}

// ---- W cast: wbf[col*256 + k] = bf16(W[k*128 + col]); block 0 inits gcur ----
__global__ void k_wcast(const float* __restrict__ W, uint16_t* __restrict__ wbf,
                        int* __restrict__ gcur, int NB) {
  int tid = threadIdx.x;
  if (blockIdx.x == 0 && tid < NB) gcur[tid] = tid * BSTRIDE;
  int t = blockIdx.x * 256 + tid;   // 32768 total
  int col = t >> 8, k = t & 255;
  wbf[t] = (uint16_t)f2bf(W[k * 128 + col]);
}

// ---- LDS-staged partition (int4-vectorized): chunk -> bucket runs -> burst out
__launch_bounds__(1024)
__global__ void k_part(const int* __restrict__ rows, const int* __restrict__ cols,
                       int E, int NB, int* __restrict__ gcur,
                       uint32_t* __restrict__ temp) {
  __shared__ uint32_t sorted[CHUNK];  // 48 KB
  __shared__ int hist[NBMAX];
  __shared__ int scanv[NBMAX];
  __shared__ int res[NBMAX];
  int tid = threadIdx.x;
  int base = blockIdx.x * CHUNK;
  int cnt = min(CHUNK, E - base);    // E,CHUNK multiples of 4 -> cnt % 4 == 0

  for (int i = tid; i < NBMAX; i += 1024) hist[i] = 0;
  __syncthreads();
  for (int i = tid * 4; i < cnt; i += 4096) {
    int4 r4 = *(const int4*)&rows[base + i];
    atomicAdd(&hist[r4.x >> RBSH], 1);
    atomicAdd(&hist[r4.y >> RBSH], 1);
    atomicAdd(&hist[r4.z >> RBSH], 1);
    atomicAdd(&hist[r4.w >> RBSH], 1);
  }
  __syncthreads();
  if (tid < NBMAX) scanv[tid] = hist[tid];
  __syncthreads();
  for (int d = 1; d < NBMAX; d <<= 1) {
    int v = 0;
    if (tid < NBMAX && tid >= d) v = scanv[tid - d];
    __syncthreads();
    if (tid < NBMAX) scanv[tid] += v;
    __syncthreads();
  }
  if (tid < NB) {
    int c = hist[tid];
    res[tid] = c ? atomicAdd(&gcur[tid], c) : 0;  // one reservation per bucket
    hist[tid] = scanv[tid] - c;                   // lbase -> cursor
  }
  __syncthreads();
  for (int i = tid * 4; i < cnt; i += 4096) {
    int4 r4 = *(const int4*)&rows[base + i];
    int4 c4 = *(const int4*)&cols[base + i];
    int p0 = atomicAdd(&hist[r4.x >> RBSH], 1);
    sorted[p0] = ((uint32_t)(r4.x & (RB - 1)) << 17) | (uint32_t)c4.x;
    int p1 = atomicAdd(&hist[r4.y >> RBSH], 1);
    sorted[p1] = ((uint32_t)(r4.y & (RB - 1)) << 17) | (uint32_t)c4.y;
    int p2 = atomicAdd(&hist[r4.z >> RBSH], 1);
    sorted[p2] = ((uint32_t)(r4.z & (RB - 1)) << 17) | (uint32_t)c4.z;
    int p3 = atomicAdd(&hist[r4.w >> RBSH], 1);
    sorted[p3] = ((uint32_t)(r4.w & (RB - 1)) << 17) | (uint32_t)c4.w;
  }
  __syncthreads();
  int wv = tid >> 6, lane = tid & 63;
  for (int b = wv; b < NB; b += 16) {   // wave-cooperative contiguous run copy
    int st = b ? scanv[b - 1] : 0;
    int en = scanv[b];
    int gb = res[b];
    for (int j = st + lane; j < en; j += 64)
      temp[gb + (j - st)] = sorted[j];
  }
}

// ---- per-bucket CSR build (1024 thr, uint4); emits deg -> dis, offs, cnts ----
__launch_bounds__(1024)
__global__ void k_csr_build(const int* __restrict__ gcur,
                            const uint32_t* __restrict__ temp, int N,
                            int* __restrict__ offs, int* __restrict__ cnts,
                            float* __restrict__ dis, int* __restrict__ csr) {
  __shared__ int cnt[RB];   // per-node count -> cursor
  __shared__ int S[256];
  int b = blockIdx.x;
  int tid = threadIdx.x;
  int base = b * BSTRIDE;   // 16B-aligned (BSTRIDE % 4 == 0)
  int cb = gcur[b] - base;
  int cb4 = cb & ~3;

  if (tid < RB) cnt[tid] = 0;
  __syncthreads();
  for (int i = tid * 4; i < cb4; i += 4096) {
    uint4 t4 = *(const uint4*)&temp[base + i];
    atomicAdd(&cnt[t4.x >> 17], 1);
    atomicAdd(&cnt[t4.y >> 17], 1);
    atomicAdd(&cnt[t4.z >> 17], 1);
    atomicAdd(&cnt[t4.w >> 17], 1);
  }
  if (tid < cb - cb4)                     // tail 0..3
    atomicAdd(&cnt[temp[base + cb4 + tid] >> 17], 1);
  __syncthreads();
  int a0 = 0, a1 = 0, ex0 = 0;
  if (tid < 256) {
    a0 = cnt[2 * tid]; a1 = cnt[2 * tid + 1];
    S[tid] = a0 + a1;
  }
  __syncthreads();
  for (int d = 1; d < 256; d <<= 1) {
    int v = 0;
    if (tid < 256 && tid >= d) v = S[tid - d];
    __syncthreads();
    if (tid < 256) S[tid] += v;
    __syncthreads();
  }
  if (tid < 256) {
    ex0 = S[tid] - (a0 + a1);
    int r0 = b * RB + 2 * tid;
    if (r0 < N) {
      dis[r0] = rsqrtf((float)(a0 + 1));
      offs[r0] = base + ex0;
      cnts[r0] = a0;
    }
    if (r0 + 1 < N) {
      dis[r0 + 1] = rsqrtf((float)(a1 + 1));
      offs[r0 + 1] = base + ex0 + a0;
      cnts[r0 + 1] = a1;
    }
  }
  __syncthreads();
  if (tid < 256) {
    cnt[2 * tid]     = ex0;       // cursor start
    cnt[2 * tid + 1] = ex0 + a0;
  }
  __syncthreads();
  for (int i = tid * 4; i < cb4; i += 4096) {
    uint4 t4 = *(const uint4*)&temp[base + i];
    int p0 = atomicAdd(&cnt[t4.x >> 17], 1);
    csr[base + p0] = (int)(t4.x & 0x1FFFF);
    int p1 = atomicAdd(&cnt[t4.y >> 17], 1);
    csr[base + p1] = (int)(t4.y & 0x1FFFF);
    int p2 = atomicAdd(&cnt[t4.z >> 17], 1);
    csr[base + p2] = (int)(t4.z & 0x1FFFF);
    int p3 = atomicAdd(&cnt[t4.w >> 17], 1);
    csr[base + p3] = (int)(t4.w & 0x1FFFF);
  }
  if (tid < cb - cb4) {
    uint32_t pk = temp[base + cb4 + tid];
    int p = atomicAdd(&cnt[pk >> 17], 1);
    csr[base + p] = (int)(pk & 0x1FFFF);
  }
}

// ---- bf16 MFMA GEMM: h = x W + b; store hu[m*64+j] = bf16(dis[m]*h) pair ----
// Block: 512 thr = 8 waves, M-tile 128, all 128 cols -> 64 KB W-LDS amortized
// at 16 waves/CU (4/SIMD). Wave w: rows [32(w&3),+32), cols [64(w>>2),+64) as
// two 32x32 tiles. A-frags straight from global (x rows used once, v_cvt_pk);
// W in LDS bf16 [col][k], 16B-slot XOR swizzle => conflict-free b128.
// hu dword j packs feats (p, p+32), p = (j&31) | ((j&32)<<1).
__launch_bounds__(512)
__global__ void k_gemm(const float* __restrict__ x, const uint16_t* __restrict__ wbf,
                       const float* __restrict__ bias, const float* __restrict__ dis,
                       uint32_t* __restrict__ hu, int M) {
  __shared__ uint16_t wlds[32768];  // 64 KB
  int tid = threadIdx.x;
  {
    const uint4* src = (const uint4*)wbf;
#pragma unroll
    for (int i = 0; i < 8; ++i) {      // 8 * 512 = 4096 chunks = full 64 KB
      int chunk = i * 512 + tid;       // 16B chunks: col = chunk>>5, slot = chunk&31
      uint4 v = src[chunk];
      int col = chunk >> 5, s = chunk & 31;
      int sp = s ^ (col & 31);
      *(uint4*)&wlds[col * 256 + sp * 8] = v;
    }
  }
  int w = tid >> 6, l = tid & 63;
  int lr = l & 31, g = l >> 5;
  int row = blockIdx.x * 128 + (w & 3) * 32 + lr;
  int c0 = (w >> 2) * 64;
  bool valid = row < M;
  const float* xrow = x + (size_t)row * 256;
  f32x16 acc0 = {}, acc1 = {};
  __syncthreads();
#pragma unroll
  for (int kt = 0; kt < 16; ++kt) {
    int k0 = kt * 16 + g * 8;          // lane's 8 contiguous k
    float4 f0 = make_float4(0.f, 0.f, 0.f, 0.f), f1 = f0;
    if (valid) {
      f0 = *(const float4*)(xrow + k0);
      f1 = *(const float4*)(xrow + k0 + 4);
    }
    union { uint32_t u[4]; short8v v; } av;
    av.u[0] = cvt_pk(f0.x, f0.y);
    av.u[1] = cvt_pk(f0.z, f0.w);
    av.u[2] = cvt_pk(f1.x, f1.y);
    av.u[3] = cvt_pk(f1.z, f1.w);
    int sp = (kt * 2 + g) ^ lr;        // swizzled 16B slot
    short8v b0 = *(short8v*)&wlds[(c0 + lr) * 256 + sp * 8];
    short8v b1 = *(short8v*)&wlds[(c0 + 32 + lr) * 256 + sp * 8];
    acc0 = __builtin_amdgcn_mfma_f32_32x32x16_bf16(av.v, b0, acc0, 0, 0, 0);
    acc1 = __builtin_amdgcn_mfma_f32_32x32x16_bf16(av.v, b1, acc1, 0, 0, 0);
  }
  int j = lr + (w >> 2) * 32;          // hu pair index
  int p = c0 + lr;                     // actual feature col of tile0
  float bl = bias[p], bh = bias[p + 32];
#pragma unroll
  for (int r = 0; r < 16; ++r) {
    int mrow = blockIdx.x * 128 + (w & 3) * 32 + (r & 3) + 8 * (r >> 2) + 4 * g;
    if (mrow < M) {
      float di = dis[mrow];
      hu[(size_t)mrow * 64 + j] = cvt_pk(di * (acc0[r] + bl), di * (acc1[r] + bh));
    }
  }
}

// ---- aggregation: wave per node, scalar addressing, 8 gathers in flight ----
// offs/cnts readfirstlane'd -> csr reads on the scalar pipe, hu row base SGPR
// + loop-invariant lane offset. Measured at the L3 random-fetch ceiling.
__launch_bounds__(256)
__global__ void k_aggregate(const uint32_t* __restrict__ hu, const float* __restrict__ dis,
                            const int* __restrict__ offs, const int* __restrict__ cnts,
                            const int* __restrict__ csr,
                            float* __restrict__ out, int N) {
  int wid = blockIdx.x * 4 + (threadIdx.x >> 6);
  int lane = threadIdx.x & 63;
  if (wid >= N) return;
  int e0  = __builtin_amdgcn_readfirstlane(offs[wid]);
  int cnt = __builtin_amdgcn_readfirstlane(cnts[wid]);
  const int* cp = csr + e0;                       // uniform (SGPR) base
  const uint32_t* hrow = hu + ((size_t)(uint32_t)wid << 6);
  uint32_t ps = hrow[lane];
  float ax = bf_lo(ps);   // self loop: hu' already has dis folded in
  float ay = bf_hi(ps);
  int i = 0;
  for (; i + 8 <= cnt; i += 8) {                  // 8 independent gathers in flight
    int c0 = cp[i],     c1 = cp[i + 1], c2 = cp[i + 2], c3 = cp[i + 3];
    int c4 = cp[i + 4], c5 = cp[i + 5], c6 = cp[i + 6], c7 = cp[i + 7];
    uint32_t p0 = hu[((size_t)(uint32_t)c0 << 6) + lane];
    uint32_t p1 = hu[((size_t)(uint32_t)c1 << 6) + lane];
    uint32_t p2 = hu[((size_t)(uint32_t)c2 << 6) + lane];
    uint32_t p3 = hu[((size_t)(uint32_t)c3 << 6) + lane];
    uint32_t p4 = hu[((size_t)(uint32_t)c4 << 6) + lane];
    uint32_t p5 = hu[((size_t)(uint32_t)c5 << 6) + lane];
    uint32_t p6 = hu[((size_t)(uint32_t)c6 << 6) + lane];
    uint32_t p7 = hu[((size_t)(uint32_t)c7 << 6) + lane];
    ax += bf_lo(p0) + bf_lo(p1) + bf_lo(p2) + bf_lo(p3)
        + bf_lo(p4) + bf_lo(p5) + bf_lo(p6) + bf_lo(p7);
    ay += bf_hi(p0) + bf_hi(p1) + bf_hi(p2) + bf_hi(p3)
        + bf_hi(p4) + bf_hi(p5) + bf_hi(p6) + bf_hi(p7);
  }
  for (; i + 4 <= cnt; i += 4) {
    int c0 = cp[i], c1 = cp[i + 1], c2 = cp[i + 2], c3 = cp[i + 3];
    uint32_t p0 = hu[((size_t)(uint32_t)c0 << 6) + lane];
    uint32_t p1 = hu[((size_t)(uint32_t)c1 << 6) + lane];
    uint32_t p2 = hu[((size_t)(uint32_t)c2 << 6) + lane];
    uint32_t p3 = hu[((size_t)(uint32_t)c3 << 6) + lane];
    ax += bf_lo(p0) + bf_lo(p1) + bf_lo(p2) + bf_lo(p3);
    ay += bf_hi(p0) + bf_hi(p1) + bf_hi(p2) + bf_hi(p3);
  }
  for (; i < cnt; ++i) {
    int c = cp[i];
    uint32_t p = hu[((size_t)(uint32_t)c << 6) + lane];
    ax += bf_lo(p);
    ay += bf_hi(p);
  }
  float di = dis[wid];
  int p = (lane & 31) | ((lane & 32) << 1);
  float* orow = out + (size_t)wid * 128;
  __builtin_nontemporal_store(di * ax, &orow[p]);
  __builtin_nontemporal_store(di * ay, &orow[p + 32]);
}

// ---- fallback path (small workspace): count -> dis -> per-edge atomics ----
__global__ void k_count(const int* __restrict__ rows, int E, int* __restrict__ deg) {
  int e = blockIdx.x * blockDim.x + threadIdx.x;
  if (e < E) atomicAdd(&deg[rows[e]], 1);
}

__global__ void k_dis(const int* __restrict__ deg, float* __restrict__ dis, int N) {
  int i = blockIdx.x * blockDim.x + threadIdx.x;
  if (i < N) dis[i] = rsqrtf((float)(deg[i] + 1));
}

__launch_bounds__(256)
__global__ void k_selfinit(const uint32_t* __restrict__ hu, const float* __restrict__ dis,
                           float* __restrict__ out, int N) {
  int wid = blockIdx.x * 4 + (threadIdx.x >> 6);
  int lane = threadIdx.x & 63;
  if (wid >= N) return;
  float di = dis[wid];
  uint32_t p = hu[(size_t)wid * 64 + lane];
  int pc = (lane & 31) | ((lane & 32) << 1);
  out[(size_t)wid * 128 + pc] = di * bf_lo(p);
  out[(size_t)wid * 128 + pc + 32] = di * bf_hi(p);
}

__launch_bounds__(256)
__global__ void k_edge_atomic(const int* __restrict__ rows, const int* __restrict__ cols, int E,
                              const uint32_t* __restrict__ hu, const float* __restrict__ dis,
                              float* __restrict__ out) {
  int wid = blockIdx.x * 4 + (threadIdx.x >> 6);
  int lane = threadIdx.x & 63;
  if (wid >= E) return;
  int r = rows[wid], c = cols[wid];
  float w = dis[r];  // hu'[c] already carries dis[c]
  uint32_t p = hu[(size_t)c * 64 + lane];
  int pc = (lane & 31) | ((lane & 32) << 1);
  atomicAdd(&out[(size_t)r * 128 + pc], w * bf_lo(p));
  atomicAdd(&out[(size_t)r * 128 + pc + 32], w * bf_hi(p));
}

extern "C" void kernel_launch(void* const* d_in, const int* in_sizes, int n_in,
                              void* d_out, int out_size, void* d_ws, size_t ws_size,
                              hipStream_t stream) {
  const float* x    = (const float*)d_in[0];
  const int*   ei   = (const int*)d_in[1];
  const float* W    = (const float*)d_in[2];
  const float* bias = (const float*)d_in[3];
  float* out = (float*)d_out;

  const int N = in_sizes[0] / 256;   // 100000
  const int E = in_sizes[1] / 2;     // 3200000
  const int NB = (N + RB - 1) / RB;  // 196 buckets of 512 rows
  const int* rows = ei;
  const int* cols = ei + E;

  // workspace layout (256B aligned slices)
  size_t off = 0;
  auto alloc = [&](size_t bytes) -> void* {
    void* p = (char*)d_ws + off;
    off += (bytes + 255) & ~(size_t)255;
    return p;
  };
  uint32_t* hu    = (uint32_t*)alloc((size_t)N * 64 * 4);  // bf16-packed dis*h
  float*    dis   = (float*)alloc((size_t)N * 4);
  int*      deg   = (int*)alloc((size_t)N * 4);            // fallback only
  uint16_t* wbf   = (uint16_t*)alloc(32768 * 2);           // bf16 W, [col][k]
  int*      gcur  = (int*)alloc((size_t)NBMAX * 4);
  int*      offs  = (int*)alloc((size_t)N * 4);
  int*      cnts  = (int*)alloc((size_t)N * 4);
  size_t small_end = off;
  uint32_t* temp  = (uint32_t*)alloc((size_t)NB * BSTRIDE * 4);
  int*      csr   = (int*)alloc((size_t)NB * BSTRIDE * 4);
  bool full = (off <= ws_size);
  bool atomic_ok = (small_end <= ws_size);

  k_wcast<<<128, 256, 0, stream>>>(W, wbf, gcur, NB);

  if (full) {
    k_part<<<(E + CHUNK - 1) / CHUNK, 1024, 0, stream>>>(rows, cols, E, NB, gcur, temp);
    k_csr_build<<<NB, 1024, 0, stream>>>(gcur, temp, N, offs, cnts, dis, csr);
    k_gemm<<<(N + 127) / 128, 512, 0, stream>>>(x, wbf, bias, dis, hu, N);
    k_aggregate<<<(N + 3) / 4, 256, 0, stream>>>(hu, dis, offs, cnts, csr, out, N);
  } else if (atomic_ok) {
    hipMemsetAsync(deg, 0, (size_t)N * 4, stream);
    k_count<<<(E + 255) / 256, 256, 0, stream>>>(rows, E, deg);
    k_dis<<<(N + 255) / 256, 256, 0, stream>>>(deg, dis, N);
    k_gemm<<<(N + 127) / 128, 512, 0, stream>>>(x, wbf, bias, dis, hu, N);
    k_selfinit<<<(N + 3) / 4, 256, 0, stream>>>(hu, dis, out, N);
    k_edge_atomic<<<(E + 3) / 4, 256, 0, stream>>>(rows, cols, E, hu, dis, out);
  }
}